// Round 1
// baseline (1066.348 us; speedup 1.0000x reference)
//
#include <hip/hip_runtime.h>
#include <math.h>

#define IN_C   128
#define OUT_C  64
#define EDIM   16
#define EHID   32
#define GN_EPS 1e-5f

__device__ __forceinline__ float dot4(float4 a, float4 b) {
    return a.x * b.x + a.y * b.y + a.z * b.z + a.w * b.w;
}

// ---------------------------------------------------------------------------
// K1: edge MLP  ew[e] = sigmoid(w2 . relu(W1 ea[e] + b1) + b2)
// one thread per edge; MLP weights staged in LDS (broadcast b128 reads, free)
// ---------------------------------------------------------------------------
__global__ void k_edge_mlp(const float* __restrict__ ea,
                           const float* __restrict__ w1, const float* __restrict__ b1,
                           const float* __restrict__ w2, const float* __restrict__ b2,
                           float* __restrict__ ew, int E) {
    __shared__ float4 sw1[EHID][4];
    __shared__ float  sb1[EHID];
    __shared__ float  sw2[EHID];
    __shared__ float  sb2;
    int tid = threadIdx.x;
    if (tid < 128) {
        const float4* w1v = (const float4*)w1;
        sw1[tid >> 2][tid & 3] = w1v[tid];
    }
    if (tid < EHID) { sb1[tid] = b1[tid]; sw2[tid] = w2[tid]; }
    if (tid == 0)   sb2 = b2[0];
    __syncthreads();

    int e = blockIdx.x * 256 + tid;
    if (e >= E) return;
    const float4* eav = (const float4*)ea + (size_t)e * 4;
    float4 a0 = eav[0], a1 = eav[1], a2 = eav[2], a3 = eav[3];
    float z = sb2;
    #pragma unroll
    for (int j = 0; j < EHID; ++j) {
        float h = dot4(a0, sw1[j][0]) + dot4(a1, sw1[j][1])
                + dot4(a2, sw1[j][2]) + dot4(a3, sw1[j][3]) + sb1[j];
        h = fmaxf(h, 0.f);
        z += h * sw2[j];
    }
    ew[e] = 1.f / (1.f + __expf(-z));
}

// ---------------------------------------------------------------------------
// K2: weighted degree (self-loop weight 1.0 folded into init) -> dinv in place
// ---------------------------------------------------------------------------
__global__ void k_init_deg(float* __restrict__ deg, int N) {
    int i = blockIdx.x * 256 + threadIdx.x;
    if (i < N) deg[i] = 1.0f;                      // self-loop weight
}

__global__ void k_deg_scatter(const int* __restrict__ ei, const float* __restrict__ ew,
                              float* __restrict__ deg, int E) {
    int e = blockIdx.x * 256 + threadIdx.x;
    if (e < E) atomicAdd(&deg[ei[E + e]], ew[e]);  // weighted degree on targets
}

__global__ void k_dinv(float* __restrict__ deg, int N) {
    int i = blockIdx.x * 256 + threadIdx.x;
    if (i < N) {
        float d = deg[i];                          // always >= 1
        deg[i] = rsqrtf(d);
    }
}

// ---------------------------------------------------------------------------
// K3: xt = x @ lin_w^T   (100k x 128) @ (128 x 64)
// block = 256 = 4 rows x 64 lanes; W^T staged in LDS as wT[k][c]
// (lane c reads wT[k][c] -> consecutive addresses, 2-way bank alias = free)
// ---------------------------------------------------------------------------
__global__ void k_xt(const float* __restrict__ x, const float* __restrict__ lw,
                     float* __restrict__ xt, int N) {
    __shared__ float swt[IN_C * OUT_C];            // 32 KiB: wT[k][c] = lw[c][k]
    int tid = threadIdx.x;
    const float4* lwv = (const float4*)lw;
    for (int i = tid; i < IN_C * OUT_C / 4; i += 256) {
        float4 v = lwv[i];
        int idx = i * 4;
        int c = idx >> 7;                          // / IN_C
        int k = idx & (IN_C - 1);
        swt[(k + 0) * OUT_C + c] = v.x;
        swt[(k + 1) * OUT_C + c] = v.y;
        swt[(k + 2) * OUT_C + c] = v.z;
        swt[(k + 3) * OUT_C + c] = v.w;
    }
    __syncthreads();

    int row  = blockIdx.x * 4 + (tid >> 6);
    int lane = tid & 63;
    if (row >= N) return;
    const float4* xr = (const float4*)(x + (size_t)row * IN_C);
    float acc = 0.f;
    #pragma unroll 8
    for (int k4 = 0; k4 < IN_C / 4; ++k4) {
        float4 xv = xr[k4];                        // wave-broadcast load (L1)
        int k = k4 * 4;
        acc += xv.x * swt[(k + 0) * OUT_C + lane];
        acc += xv.y * swt[(k + 1) * OUT_C + lane];
        acc += xv.z * swt[(k + 2) * OUT_C + lane];
        acc += xv.w * swt[(k + 3) * OUT_C + lane];
    }
    xt[(size_t)row * OUT_C + lane] = acc;
}

// ---------------------------------------------------------------------------
// K4: out init = bias + self-loop message dinv[i]^2 * xt[i]
// ---------------------------------------------------------------------------
__global__ void k_init_out(const float* __restrict__ bias, const float* __restrict__ dinv,
                           const float* __restrict__ xt, float* __restrict__ out, int total) {
    int t = blockIdx.x * 256 + threadIdx.x;
    if (t >= total) return;
    int i = t >> 6, c = t & 63;
    float di = dinv[i];
    out[t] = bias[c] + di * di * xt[t];
}

// ---------------------------------------------------------------------------
// K5: message scatter — one wave per edge, lane = channel.
// idx/ew/dinv loads are wave-uniform (broadcast); xt gather coalesced 256 B;
// 64 f32 atomics per edge into out[col].
// ---------------------------------------------------------------------------
__global__ void k_scatter(const int* __restrict__ ei, const float* __restrict__ ew,
                          const float* __restrict__ dinv, const float* __restrict__ xt,
                          float* __restrict__ out, int E) {
    int t = blockIdx.x * 256 + threadIdx.x;
    int e = t >> 6;
    if (e >= E) return;
    int lane = t & 63;
    int row = ei[e];
    int col = ei[E + e];
    float w = dinv[row] * ew[e] * dinv[col];
    atomicAdd(out + (size_t)col * OUT_C + lane, w * xt[(size_t)row * OUT_C + lane]);
}

// ---------------------------------------------------------------------------
// K6/K7/K8: PReLU + GraphNorm (sum/sumsq pass, then fused apply)
// ---------------------------------------------------------------------------
__global__ void k_zero_stats(float* __restrict__ sums) {
    int t = threadIdx.x;
    if (t < 2 * OUT_C) sums[t] = 0.f;
}

__global__ void k_stats(const float* __restrict__ out, const float* __restrict__ pa,
                        float* __restrict__ sums, int total) {
    __shared__ float r1[256], r2[256];
    float a = pa[0];
    float s = 0.f, s2 = 0.f;
    int stride = gridDim.x * 256;
    for (int t = blockIdx.x * 256 + threadIdx.x; t < total; t += stride) {
        float v = out[t];
        float y = v >= 0.f ? v : a * v;            // PReLU
        s += y; s2 += y * y;
    }
    int tid = threadIdx.x;
    r1[tid] = s; r2[tid] = s2;
    __syncthreads();
    if (tid < 64) {   // stride is a multiple of 64 -> channel == tid & 63 for all four
        float t1 = r1[tid] + r1[tid + 64] + r1[tid + 128] + r1[tid + 192];
        float t2 = r2[tid] + r2[tid + 64] + r2[tid + 128] + r2[tid + 192];
        atomicAdd(&sums[tid], t1);
        atomicAdd(&sums[OUT_C + tid], t2);
    }
}

__global__ void k_apply(float* __restrict__ out, const float* __restrict__ pa,
                        const float* __restrict__ sums,
                        const float* __restrict__ gw, const float* __restrict__ gb,
                        const float* __restrict__ gms, int total, float invN) {
    int t = blockIdx.x * 256 + threadIdx.x;
    if (t >= total) return;
    int c = t & 63;
    float a  = pa[0];
    float m  = sums[c] * invN;
    float ms = gms[c];
    // var = E[y^2] - 2*s*m*E[y] + s^2 m^2 = E[y^2] - s*m^2*(2 - s)
    float var = sums[OUT_C + c] * invN - ms * m * m * (2.f - ms);
    float A = gw[c] * rsqrtf(var + GN_EPS);
    float v = out[t];
    float y = v >= 0.f ? v : a * v;                // PReLU
    out[t] = A * (y - ms * m) + gb[c];
}

// ---------------------------------------------------------------------------
extern "C" void kernel_launch(void* const* d_in, const int* in_sizes, int n_in,
                              void* d_out, int out_size, void* d_ws, size_t ws_size,
                              hipStream_t stream) {
    const float* x    = (const float*)d_in[0];
    const int*   ei   = (const int*)  d_in[1];   // [2,E] row-major int32
    const float* ea   = (const float*)d_in[2];
    const float* lw   = (const float*)d_in[3];
    const float* bias = (const float*)d_in[4];
    const float* w1   = (const float*)d_in[5];
    const float* b1   = (const float*)d_in[6];
    const float* w2   = (const float*)d_in[7];
    const float* b2   = (const float*)d_in[8];
    const float* pa   = (const float*)d_in[9];
    const float* gw   = (const float*)d_in[10];
    const float* gb   = (const float*)d_in[11];
    const float* gms  = (const float*)d_in[12];
    float* out = (float*)d_out;

    int N = in_sizes[0] / IN_C;
    int E = in_sizes[2] / EDIM;
    int total = N * OUT_C;

    // workspace layout (floats): ew[E] | dinv[N] | xt[N*64] | sums[128]
    float* ew   = (float*)d_ws;
    float* dinv = ew + E;
    float* xt   = dinv + N;
    float* sums = xt + (size_t)N * OUT_C;

    k_edge_mlp  <<<(E + 255) / 256, 256, 0, stream>>>(ea, w1, b1, w2, b2, ew, E);
    k_init_deg  <<<(N + 255) / 256, 256, 0, stream>>>(dinv, N);
    k_deg_scatter<<<(E + 255) / 256, 256, 0, stream>>>(ei, ew, dinv, E);
    k_dinv      <<<(N + 255) / 256, 256, 0, stream>>>(dinv, N);
    k_xt        <<<(N + 3) / 4, 256, 0, stream>>>(x, lw, xt, N);
    k_init_out  <<<(total + 255) / 256, 256, 0, stream>>>(bias, dinv, xt, out, total);
    long scatter_threads = (long)E * 64;
    k_scatter   <<<(unsigned)((scatter_threads + 255) / 256), 256, 0, stream>>>(ei, ew, dinv, xt, out, E);
    k_zero_stats<<<1, 128, 0, stream>>>(sums);
    k_stats     <<<512, 256, 0, stream>>>(out, pa, sums, total);
    k_apply     <<<(total + 255) / 256, 256, 0, stream>>>(out, pa, sums, gw, gb, gms, total,
                                                          1.0f / (float)N);
}

// Round 3
// 651.944 us; speedup vs baseline: 1.6356x; 1.6356x over previous
//
#include <hip/hip_runtime.h>
#include <math.h>

#define IN_C   128
#define OUT_C  64
#define EDIM   16
#define EHID   32
#define GN_EPS 1e-5f

__device__ __forceinline__ float dot4(float4 a, float4 b) {
    return a.x * b.x + a.y * b.y + a.z * b.z + a.w * b.w;
}
__device__ __forceinline__ void fma4(float4& a, float s, float4 w) {
    a.x = fmaf(s, w.x, a.x); a.y = fmaf(s, w.y, a.y);
    a.z = fmaf(s, w.z, a.z); a.w = fmaf(s, w.w, a.w);
}
__device__ __forceinline__ float getc(float4 v, int j) {
    return j == 0 ? v.x : j == 1 ? v.y : j == 2 ? v.z : v.w;
}

// ---------------------------------------------------------------------------
// K1: edge MLP  ew[e] = sigmoid(w2 . relu(W1 ea[e] + b1) + b2)
// ---------------------------------------------------------------------------
__global__ void k_edge_mlp(const float* __restrict__ ea,
                           const float* __restrict__ w1, const float* __restrict__ b1,
                           const float* __restrict__ w2, const float* __restrict__ b2,
                           float* __restrict__ ew, int E) {
    __shared__ float4 sw1[EHID][4];
    __shared__ float  sb1[EHID];
    __shared__ float  sw2[EHID];
    __shared__ float  sb2;
    int tid = threadIdx.x;
    if (tid < 128) {
        const float4* w1v = (const float4*)w1;
        sw1[tid >> 2][tid & 3] = w1v[tid];
    }
    if (tid < EHID) { sb1[tid] = b1[tid]; sw2[tid] = w2[tid]; }
    if (tid == 0)   sb2 = b2[0];
    __syncthreads();

    int e = blockIdx.x * 256 + tid;
    if (e >= E) return;
    const float4* eav = (const float4*)ea + (size_t)e * 4;
    float4 a0 = eav[0], a1 = eav[1], a2 = eav[2], a3 = eav[3];
    float z = sb2;
    #pragma unroll
    for (int j = 0; j < EHID; ++j) {
        float h = dot4(a0, sw1[j][0]) + dot4(a1, sw1[j][1])
                + dot4(a2, sw1[j][2]) + dot4(a3, sw1[j][3]) + sb1[j];
        h = fmaxf(h, 0.f);
        z += h * sw2[j];
    }
    ew[e] = 1.f / (1.f + __expf(-z));
}

// ---------------------------------------------------------------------------
// K2: weighted degree (self-loop folded into init = 1.0) -> dinv in place
// ---------------------------------------------------------------------------
__global__ void k_init_deg(float* __restrict__ deg, int N) {
    int i = blockIdx.x * 256 + threadIdx.x;
    if (i < N) deg[i] = 1.0f;
}
__global__ void k_deg_scatter(const int* __restrict__ ei, const float* __restrict__ ew,
                              float* __restrict__ deg, int E) {
    int e = blockIdx.x * 256 + threadIdx.x;
    if (e < E) atomicAdd(&deg[ei[E + e]], ew[e]);
}
__global__ void k_dinv(float* __restrict__ deg, int N) {
    int i = blockIdx.x * 256 + threadIdx.x;
    if (i < N) deg[i] = rsqrtf(deg[i]);
}

// ---------------------------------------------------------------------------
// K3: xt = x @ lin_w^T  — register-tiled: lane = (c4, rq), 4 rows x 4 ch/lane,
// 64 rows per block. swt[k][c] staged once; b128 reads, 2-way alias only.
// ---------------------------------------------------------------------------
__global__ void k_xt(const float* __restrict__ x, const float* __restrict__ lw,
                     float* __restrict__ xt, int N) {
    __shared__ float swt[IN_C * OUT_C];            // swt[k*64 + c] = lw[c*128 + k]
    int tid = threadIdx.x;
    for (int i = tid; i < IN_C * OUT_C; i += 256) {
        int k = i >> 6, c = i & 63;
        swt[i] = lw[c * IN_C + k];                 // consecutive LDS writes
    }
    __syncthreads();

    int lane = tid & 63;
    int c4 = lane & 15;                            // channel group: 4*c4..4*c4+3
    int rq = lane >> 4;                            // row quad within wave
    int rbase = blockIdx.x * 64 + (tid >> 6) * 16 + rq * 4;

    int r0 = min(rbase + 0, N - 1), r1 = min(rbase + 1, N - 1);
    int r2 = min(rbase + 2, N - 1), r3 = min(rbase + 3, N - 1);
    const float4* x4 = (const float4*)x;
    float4 acc0 = {0,0,0,0}, acc1 = {0,0,0,0}, acc2 = {0,0,0,0}, acc3 = {0,0,0,0};

    #pragma unroll 4
    for (int k4 = 0; k4 < IN_C / 4; ++k4) {
        float4 xv0 = x4[(size_t)r0 * 32 + k4];
        float4 xv1 = x4[(size_t)r1 * 32 + k4];
        float4 xv2 = x4[(size_t)r2 * 32 + k4];
        float4 xv3 = x4[(size_t)r3 * 32 + k4];
        #pragma unroll
        for (int j = 0; j < 4; ++j) {
            float4 wv = *(const float4*)&swt[(k4 * 4 + j) * OUT_C + (c4 << 2)];
            fma4(acc0, getc(xv0, j), wv);
            fma4(acc1, getc(xv1, j), wv);
            fma4(acc2, getc(xv2, j), wv);
            fma4(acc3, getc(xv3, j), wv);
        }
    }
    int cc = c4 << 2;
    if (rbase + 0 < N) *(float4*)&xt[(size_t)(rbase + 0) * OUT_C + cc] = acc0;
    if (rbase + 1 < N) *(float4*)&xt[(size_t)(rbase + 1) * OUT_C + cc] = acc1;
    if (rbase + 2 < N) *(float4*)&xt[(size_t)(rbase + 2) * OUT_C + cc] = acc2;
    if (rbase + 3 < N) *(float4*)&xt[(size_t)(rbase + 3) * OUT_C + cc] = acc3;
}

// ---------------------------------------------------------------------------
// CSR build: histogram -> block scan -> scan of block sums -> add + reset
// ---------------------------------------------------------------------------
__global__ void k_zero_cnt(int* __restrict__ cnt, int N) {
    int i = blockIdx.x * 256 + threadIdx.x;
    if (i < N) cnt[i] = 0;
}
__global__ void k_hist(const int* __restrict__ ei, int* __restrict__ cnt, int E) {
    int e = blockIdx.x * 256 + threadIdx.x;
    if (e < E) atomicAdd(&cnt[ei[E + e]], 1);
}
__global__ void k_scan1(const int* __restrict__ cnt, int* __restrict__ start,
                        int* __restrict__ bsums, int N) {
    __shared__ int s[256];
    int t = threadIdx.x;
    int i = blockIdx.x * 256 + t;
    int v = (i < N) ? cnt[i] : 0;
    s[t] = v;
    __syncthreads();
    #pragma unroll
    for (int off = 1; off < 256; off <<= 1) {
        int u = (t >= off) ? s[t - off] : 0;
        __syncthreads();
        s[t] += u;
        __syncthreads();
    }
    if (i < N) start[i] = s[t] - v;                // exclusive within block
    if (t == 255) bsums[blockIdx.x] = s[255];
}
__global__ void k_scan2(int* __restrict__ bsums, int nb) {
    __shared__ int s[1024];
    int t = threadIdx.x;
    s[t] = (t < nb) ? bsums[t] : 0;
    __syncthreads();
    #pragma unroll
    for (int off = 1; off < 1024; off <<= 1) {
        int u = (t >= off) ? s[t - off] : 0;
        __syncthreads();
        s[t] += u;
        __syncthreads();
    }
    if (t < nb) bsums[t] = (t == 0) ? 0 : s[t - 1];   // exclusive
}
__global__ void k_scan3(int* __restrict__ start, const int* __restrict__ bsums,
                        int* __restrict__ cnt, int N) {
    int i = blockIdx.x * 256 + threadIdx.x;
    if (i < N) {
        start[i] += bsums[blockIdx.x];
        cnt[i] = 0;                                // reuse as rank counters
    }
}
// scatter (row, norm-weight) into col-sorted order
__global__ void k_pass2(const int* __restrict__ ei, const float* __restrict__ ew,
                        const float* __restrict__ dinv, const int* __restrict__ start,
                        int* __restrict__ cnt, int* __restrict__ srow,
                        float* __restrict__ sw, int E) {
    int e = blockIdx.x * 256 + threadIdx.x;
    if (e >= E) return;
    int row = ei[e];
    int col = ei[E + e];
    float w = dinv[row] * ew[e] * dinv[col];
    int pos = start[col] + atomicAdd(&cnt[col], 1);
    srow[pos] = row;
    sw[pos] = w;
}

// ---------------------------------------------------------------------------
// Gather: one wave per node, lane = channel. No atomics; self-loop + bias fused.
// ---------------------------------------------------------------------------
__global__ void k_gather(const int* __restrict__ srow, const float* __restrict__ sw,
                         const int* __restrict__ start, const int* __restrict__ cnt,
                         const float* __restrict__ dinv, const float* __restrict__ xt,
                         const float* __restrict__ bias, float* __restrict__ out, int N) {
    int node = blockIdx.x * 4 + (threadIdx.x >> 6);
    if (node >= N) return;
    int lane = threadIdx.x & 63;
    int beg = start[node], num = cnt[node];
    float di = dinv[node];
    float acc = di * di * xt[(size_t)node * OUT_C + lane];   // self-loop message
    int j = 0;
    for (; j + 4 <= num; j += 4) {
        int   r0 = srow[beg + j + 0], r1 = srow[beg + j + 1];
        int   r2 = srow[beg + j + 2], r3 = srow[beg + j + 3];
        float w0 = sw[beg + j + 0],  w1 = sw[beg + j + 1];
        float w2 = sw[beg + j + 2],  w3 = sw[beg + j + 3];
        acc += w0 * xt[(size_t)r0 * OUT_C + lane];
        acc += w1 * xt[(size_t)r1 * OUT_C + lane];
        acc += w2 * xt[(size_t)r2 * OUT_C + lane];
        acc += w3 * xt[(size_t)r3 * OUT_C + lane];
    }
    for (; j < num; ++j) {
        acc += sw[beg + j] * xt[(size_t)srow[beg + j] * OUT_C + lane];
    }
    out[(size_t)node * OUT_C + lane] = bias[lane] + acc;
}

// ---------------------------------------------------------------------------
// Fallback (atomic) message path — used only if ws_size too small for CSR
// ---------------------------------------------------------------------------
__global__ void k_init_out(const float* __restrict__ bias, const float* __restrict__ dinv,
                           const float* __restrict__ xt, float* __restrict__ out, int total) {
    int t = blockIdx.x * 256 + threadIdx.x;
    if (t >= total) return;
    int i = t >> 6, c = t & 63;
    float di = dinv[i];
    out[t] = bias[c] + di * di * xt[t];
}
__global__ void k_scatter(const int* __restrict__ ei, const float* __restrict__ ew,
                          const float* __restrict__ dinv, const float* __restrict__ xt,
                          float* __restrict__ out, int E) {
    int t = blockIdx.x * 256 + threadIdx.x;
    int e = t >> 6;
    if (e >= E) return;
    int lane = t & 63;
    int row = ei[e];
    int col = ei[E + e];
    float w = dinv[row] * ew[e] * dinv[col];
    atomicAdd(out + (size_t)col * OUT_C + lane, w * xt[(size_t)row * OUT_C + lane]);
}

// ---------------------------------------------------------------------------
// PReLU + GraphNorm
// ---------------------------------------------------------------------------
__global__ void k_zero_stats(float* __restrict__ sums) {
    int t = threadIdx.x;
    if (t < 2 * OUT_C) sums[t] = 0.f;
}
__global__ void k_stats(const float* __restrict__ out, const float* __restrict__ pa,
                        float* __restrict__ sums, int total) {
    __shared__ float r1[256], r2[256];
    float a = pa[0];
    float s = 0.f, s2 = 0.f;
    int stride = gridDim.x * 256;
    for (int t = blockIdx.x * 256 + threadIdx.x; t < total; t += stride) {
        float v = out[t];
        float y = v >= 0.f ? v : a * v;
        s += y; s2 += y * y;
    }
    int tid = threadIdx.x;
    r1[tid] = s; r2[tid] = s2;
    __syncthreads();
    if (tid < 64) {
        float t1 = r1[tid] + r1[tid + 64] + r1[tid + 128] + r1[tid + 192];
        float t2 = r2[tid] + r2[tid + 64] + r2[tid + 128] + r2[tid + 192];
        atomicAdd(&sums[tid], t1);
        atomicAdd(&sums[OUT_C + tid], t2);
    }
}
__global__ void k_apply(float* __restrict__ out, const float* __restrict__ pa,
                        const float* __restrict__ sums,
                        const float* __restrict__ gw, const float* __restrict__ gb,
                        const float* __restrict__ gms, int total, float invN) {
    int t = blockIdx.x * 256 + threadIdx.x;
    if (t >= total) return;
    int c = t & 63;
    float a  = pa[0];
    float m  = sums[c] * invN;
    float ms = gms[c];
    float var = sums[OUT_C + c] * invN - ms * m * m * (2.f - ms);
    float A = gw[c] * rsqrtf(var + GN_EPS);
    float v = out[t];
    float y = v >= 0.f ? v : a * v;
    out[t] = A * (y - ms * m) + gb[c];
}

// ---------------------------------------------------------------------------
extern "C" void kernel_launch(void* const* d_in, const int* in_sizes, int n_in,
                              void* d_out, int out_size, void* d_ws, size_t ws_size,
                              hipStream_t stream) {
    (void)n_in; (void)out_size;
    const float* x    = (const float*)d_in[0];
    const int*   ei   = (const int*)  d_in[1];   // [2,E] row-major int32
    const float* ea   = (const float*)d_in[2];
    const float* lw   = (const float*)d_in[3];
    const float* bias = (const float*)d_in[4];
    const float* w1   = (const float*)d_in[5];
    const float* b1   = (const float*)d_in[6];
    const float* w2   = (const float*)d_in[7];
    const float* b2   = (const float*)d_in[8];
    const float* pa   = (const float*)d_in[9];
    const float* gw   = (const float*)d_in[10];
    const float* gb   = (const float*)d_in[11];
    const float* gms  = (const float*)d_in[12];
    float* out = (float*)d_out;

    int N = in_sizes[0] / IN_C;
    int E = in_sizes[2] / EDIM;
    int total = N * OUT_C;
    int nbN = (N + 255) / 256;
    int nbE = (E + 255) / 256;

    // workspace layout
    char* p = (char*)d_ws;
    float* ew    = (float*)p;  p += sizeof(float) * (size_t)E;
    float* dinv  = (float*)p;  p += sizeof(float) * (size_t)N;
    float* xt    = (float*)p;  p += sizeof(float) * (size_t)N * OUT_C;
    float* sums  = (float*)p;  p += sizeof(float) * 128;
    int*   cnt   = (int*)p;    p += sizeof(int) * (size_t)N;
    int*   startv= (int*)p;    p += sizeof(int) * (size_t)N;
    int*   bsums = (int*)p;    p += sizeof(int) * 1024;
    int*   srow  = (int*)p;    p += sizeof(int) * (size_t)E;
    float* sw    = (float*)p;  p += sizeof(float) * (size_t)E;
    size_t need = (size_t)(p - (char*)d_ws);
    bool use_csr = (need <= ws_size) && (nbN <= 1024);

    k_edge_mlp   <<<nbE, 256, 0, stream>>>(ea, w1, b1, w2, b2, ew, E);
    k_init_deg   <<<nbN, 256, 0, stream>>>(dinv, N);
    k_deg_scatter<<<nbE, 256, 0, stream>>>(ei, ew, dinv, E);
    k_dinv       <<<nbN, 256, 0, stream>>>(dinv, N);
    k_xt         <<<(N + 63) / 64, 256, 0, stream>>>(x, lw, xt, N);

    if (use_csr) {
        k_zero_cnt<<<nbN, 256, 0, stream>>>(cnt, N);
        k_hist    <<<nbE, 256, 0, stream>>>(ei, cnt, E);
        k_scan1   <<<nbN, 256, 0, stream>>>(cnt, startv, bsums, N);
        k_scan2   <<<1, 1024, 0, stream>>>(bsums, nbN);
        k_scan3   <<<nbN, 256, 0, stream>>>(startv, bsums, cnt, N);
        k_pass2   <<<nbE, 256, 0, stream>>>(ei, ew, dinv, startv, cnt, srow, sw, E);
        k_gather  <<<(N + 3) / 4, 256, 0, stream>>>(srow, sw, startv, cnt, dinv, xt, bias, out, N);
    } else {
        k_init_out<<<(total + 255) / 256, 256, 0, stream>>>(bias, dinv, xt, out, total);
        long st = (long)E * 64;
        k_scatter <<<(unsigned)((st + 255) / 256), 256, 0, stream>>>(ei, ew, dinv, xt, out, E);
    }

    k_zero_stats<<<1, 128, 0, stream>>>(sums);
    k_stats     <<<512, 256, 0, stream>>>(out, pa, sums, total);
    k_apply     <<<(total + 255) / 256, 256, 0, stream>>>(out, pa, sums, gw, gb, gms, total,
                                                          1.0f / (float)N);
}